// Round 7
// baseline (314.578 us; speedup 1.0000x reference)
//
#include <hip/hip_runtime.h>
#include <hip/hip_bf16.h>

typedef unsigned short ushort_t;
typedef unsigned int u32;
typedef __bf16 bf16x8 __attribute__((ext_vector_type(8)));
typedef float f32x4 __attribute__((ext_vector_type(4)));

#define B_ 2
#define L_ 2048
#define E_ 2048
#define HQ_ 16
#define HKV_ 2
#define D_ 128
#define NQKV 2560   // HQ*D + 2*HKV*D
#define SCALE 0.08838834764831845f
#define LOG2E 1.4426950408889634f
#define C_MAX 14.426950408889634f   // 10 * log2(e): fixed softmax max (scores |S| <~ 5)
#define NEG_INF_ -1e30f

__device__ __forceinline__ ushort_t f2bf(float f) {
    unsigned int u = __builtin_bit_cast(unsigned int, f);
    u = (u + 0x7fffu + ((u >> 16) & 1u)) >> 16;
    return (ushort_t)u;
}
__device__ __forceinline__ ushort_t f2bf_fast(float f) {
    unsigned int u = __builtin_bit_cast(unsigned int, f);
    return (ushort_t)((u + 0x8000u) >> 16);
}
__device__ __forceinline__ float bf2f(ushort_t u) {
    return __builtin_bit_cast(float, (unsigned int)u << 16);
}
__device__ __forceinline__ bf16x8 ld16(const ushort_t* p) {
    uint4 u = *reinterpret_cast<const uint4*>(p);
    return __builtin_bit_cast(bf16x8, u);
}
// async global->LDS, 16B per lane; lds dest lands at wave-uniform base + lane*16
__device__ __forceinline__ void g2lds16(const ushort_t* g, ushort_t* l) {
    __builtin_amdgcn_global_load_lds((const __attribute__((address_space(1))) u32*)g,
                                     (__attribute__((address_space(3))) u32*)l, 16, 0, 0);
}

// ================= prep: hs cast + 4 weight transposes + bias concat (fused) ==========
__global__ __launch_bounds__(256) void prep(const float* __restrict__ hs,
                                            const float* __restrict__ Wq,
                                            const float* __restrict__ Wk,
                                            const float* __restrict__ Wv,
                                            const float* __restrict__ Wo,
                                            const float* __restrict__ bq,
                                            const float* __restrict__ bk,
                                            const float* __restrict__ bv,
                                            ushort_t* __restrict__ hsb,
                                            ushort_t* __restrict__ Wqkv_t,
                                            ushort_t* __restrict__ Wo_t,
                                            float* __restrict__ biasf) {
    __shared__ float tile[32][33];
    int bid = blockIdx.x;
    if (bid < 8192) {   // cast hs -> bf16, float4/thread
        int i = bid * 256 + threadIdx.x;
        float4 f = reinterpret_cast<const float4*>(hs)[i];
        ushort4 u;
        u.x = f2bf(f.x); u.y = f2bf(f.y); u.z = f2bf(f.z); u.w = f2bf(f.w);
        reinterpret_cast<ushort4*>(hsb)[i] = u;
        return;
    }
    if (bid >= 17408) {  // bias concat
        int n = (bid - 17408) * 256 + threadIdx.x;
        if (n < NQKV) {
            float v;
            if (n < 2048) v = bq[n];
            else if (n < 2304) v = bk[n - 2048];
            else v = bv[n - 2304];
            biasf[n] = v;
        }
        return;
    }
    const float* in; ushort_t* out; int in_stride, gx, gy;
    if (bid < 12288)      { int t = bid - 8192;  gx = t & 63; gy = t >> 6; in = Wq; out = Wqkv_t;               in_stride = 2048; }
    else if (bid < 12800) { int t = bid - 12288; gx = t & 7;  gy = t >> 3; in = Wk; out = Wqkv_t + 2048 * 2048; in_stride = 256;  }
    else if (bid < 13312) { int t = bid - 12800; gx = t & 7;  gy = t >> 3; in = Wv; out = Wqkv_t + 2304 * 2048; in_stride = 256;  }
    else                  { int t = bid - 13312; gx = t & 63; gy = t >> 6; in = Wo; out = Wo_t;                 in_stride = 2048; }
    int tx = threadIdx.x & 31, ty = threadIdx.x >> 5;
    int c0 = gx * 32, r0 = gy * 32;
    #pragma unroll
    for (int k = 0; k < 4; k++)
        tile[ty + k * 8][tx] = in[(size_t)(r0 + ty + k * 8) * in_stride + c0 + tx];
    __syncthreads();
    #pragma unroll
    for (int k = 0; k < 4; k++)
        out[(size_t)(c0 + ty + k * 8) * 2048 + r0 + tx] = f2bf(tile[tx][ty + k * 8]);
}

// ================= mid: rope_q + rope_k + V transposes (fused) =========================
__global__ __launch_bounds__(256) void mid(const ushort_t* __restrict__ qkv,
                                           ushort_t* __restrict__ Q,
                                           ushort_t* __restrict__ K,
                                           ushort_t* __restrict__ Vt) {
    __shared__ ushort_t tile[32][33];
    int bid = blockIdx.x;
    if (bid < 16384) {   // rope_q (pre-scaled by SCALE*log2e for exp2-domain softmax)
        int idx = bid * 256 + threadIdx.x;
        int i = idx & 63;
        int h = (idx >> 6) & 15;
        int l = (idx >> 10) & 2047;
        int b = idx >> 21;
        const ushort_t* src = qkv + (size_t)(b * L_ + l) * NQKV + h * D_;
        float x1 = bf2f(src[i]), x2 = bf2f(src[i + 64]);
        float invf = __expf(-(float)i * (13.815510557964274f / 64.0f));
        float fr = (float)l * invf;
        float c = cosf(fr), s = sinf(fr);
        ushort_t* dst = Q + (size_t)((b * HQ_ + h) * L_ + l) * D_;
        const float SC = SCALE * LOG2E;
        dst[i] = f2bf((x1 * c - x2 * s) * SC);
        dst[i + 64] = f2bf((x2 * c + x1 * s) * SC);
        return;
    }
    if (bid < 18432) {   // rope_k
        int idx = (bid - 16384) * 256 + threadIdx.x;
        int i = idx & 63;
        int h = (idx >> 6) & 1;
        int l = (idx >> 7) & 2047;
        int b = idx >> 18;
        const ushort_t* src = qkv + (size_t)(b * L_ + l) * NQKV + 2048 + h * D_;
        float x1 = bf2f(src[i]), x2 = bf2f(src[i + 64]);
        float invf = __expf(-(float)i * (13.815510557964274f / 64.0f));
        float fr = (float)l * invf;
        float c = cosf(fr), s = sinf(fr);
        ushort_t* dst = K + (size_t)((b * HKV_ + h) * L_ + l) * D_;
        dst[i] = f2bf(x1 * c - x2 * s);
        dst[i + 64] = f2bf(x2 * c + x1 * s);
        return;
    }
    // V transpose: Vt[b][kv][d][l] = qkv[b,l][2304 + kv*128 + d]
    int t = bid - 18432;           // [0,1024)
    int z = t >> 8, rem = t & 255;
    int gx = rem & 3, gy = rem >> 2;
    int b = z >> 1, kvh = z & 1;
    const ushort_t* in = qkv + (size_t)(b * L_) * NQKV + 2304 + kvh * D_;
    ushort_t* out = Vt + (size_t)(b * HKV_ + kvh) * D_ * L_;
    int tx = threadIdx.x & 31, ty = threadIdx.x >> 5;
    int c0 = gx * 32, r0 = gy * 32;
    #pragma unroll
    for (int k = 0; k < 4; k++)
        tile[ty + k * 8][tx] = in[(size_t)(r0 + ty + k * 8) * NQKV + c0 + tx];
    __syncthreads();
    #pragma unroll
    for (int k = 0; k < 4; k++)
        out[(size_t)(c0 + ty + k * 8) * L_ + r0 + tx] = tile[tx][ty + k * 8];
}

// ---------------- LDS-staged GEMM, tile 64(M) x 128(N), BK=32 ----------------
// 4 waves as 2x2, wave tile 32x64 (acc[2][4]). Grid: (N/128, M/64) -> 2x the blocks of
// the 128x128 version; occupancy-starved shapes (grid ~2.5/CU) become 4-5 blocks/CU.
template <bool F32OUT>
__global__ __launch_bounds__(256, 4) void gemm_lds(const ushort_t* __restrict__ A,
                                                   const ushort_t* __restrict__ Bt,
                                                   const float* __restrict__ bias,
                                                   void* __restrict__ Cv,
                                                   int M, int N, int Kd) {
    __shared__ ushort_t As[64 * 32];    // 4 KB
    __shared__ ushort_t Bs[128 * 32];   // 8 KB
    int lane = threadIdx.x & 63, wave = threadIdx.x >> 6;
    int quad = lane >> 4, l16 = lane & 15;
    int wm = wave >> 1, wn = wave & 1;
    int m0 = blockIdx.y * 64, n0 = blockIdx.x * 128;

    f32x4 acc[2][4];
    #pragma unroll
    for (int i = 0; i < 2; i++)
        #pragma unroll
        for (int j = 0; j < 4; j++) acc[i][j] = (f32x4){0.f, 0.f, 0.f, 0.f};

    int rA = (lane >> 2);          // row within 16-row chunk
    int colh = (lane & 3) * 8;     // halfword col offset
    for (int k0 = 0; k0 < Kd; k0 += 32) {
        __syncthreads();
        // A: 4 chunks, wave w stages chunk w
        g2lds16(A + (size_t)(m0 + wave * 16 + rA) * Kd + k0 + colh, As + wave * 512 + lane * 8);
        // B: 8 chunks, wave w stages chunks {2w, 2w+1}
        #pragma unroll
        for (int q = 0; q < 2; q++) {
            int chunk = wave * 2 + q;
            g2lds16(Bt + (size_t)(n0 + chunk * 16 + rA) * Kd + k0 + colh, Bs + chunk * 512 + lane * 8);
        }
        __syncthreads();
        bf16x8 af[2], bfr[4];
        #pragma unroll
        for (int i = 0; i < 2; i++) af[i]  = ld16(As + (wm * 32 + i * 16 + l16) * 32 + quad * 8);
        #pragma unroll
        for (int j = 0; j < 4; j++) bfr[j] = ld16(Bs + (wn * 64 + j * 16 + l16) * 32 + quad * 8);
        #pragma unroll
        for (int i = 0; i < 2; i++)
            #pragma unroll
            for (int j = 0; j < 4; j++)
                acc[i][j] = __builtin_amdgcn_mfma_f32_16x16x32_bf16(af[i], bfr[j], acc[i][j], 0, 0, 0);
    }

    #pragma unroll
    for (int i = 0; i < 2; i++) {
        #pragma unroll
        for (int j = 0; j < 4; j++) {
            #pragma unroll
            for (int r = 0; r < 4; r++) {
                int row = m0 + wm * 32 + 16 * i + quad * 4 + r;
                int col = n0 + wn * 64 + 16 * j + l16;
                float v = acc[i][j][r];
                if (bias) v += bias[col];
                if (F32OUT) ((float*)Cv)[(size_t)row * N + col] = v;
                else        ((ushort_t*)Cv)[(size_t)row * N + col] = f2bf(v);
            }
        }
    }
}

// ---------------- flash attention: LDS-staged K/V, double-buffered, fixed-max softmax ----
__global__ __launch_bounds__(256, 2) void flash_attn(const ushort_t* __restrict__ Q,
                                                     const ushort_t* __restrict__ K,
                                                     const ushort_t* __restrict__ Vt,
                                                     ushort_t* __restrict__ Out) {
    __shared__ ushort_t Ks[2][64 * 128];
    __shared__ ushort_t Vs[2][128 * 64];
    __shared__ ushort_t ldsP[4][16][72];

    int idx = blockIdx.x;
    int x = idx & 7, j5 = idx >> 3;
    int cc = x >> 1, sub = x & 1;
    int hh = (j5 & 3) * 2 + sub;
    int p = j5 >> 2;
    int b = cc >> 1, kv = cc & 1;
    int h = kv * 8 + hh;

    int lane = threadIdx.x & 63, wave = threadIdx.x >> 6;
    int quad = lane >> 4, l16 = lane & 15;

    const ushort_t* khead = K + (b * HKV_ + kv) * L_ * D_;
    const ushort_t* vhead = Vt + (b * HKV_ + kv) * D_ * L_;

    #pragma unroll 1
    for (int ti = 0; ti < 2; ti++) {
        int t = ti ? (31 - p) : p;
        int qrow0 = t * 64 + wave * 16;

        bf16x8 aq[4];
        const ushort_t* qbase = Q + ((b * HQ_ + h) * L_ + qrow0 + l16) * D_ + quad * 8;
        #pragma unroll
        for (int kk = 0; kk < 4; kk++) aq[kk] = ld16(qbase + 32 * kk);

        f32x4 o[8];
        #pragma unroll
        for (int i = 0; i < 8; i++) o[i] = (f32x4){0.f, 0.f, 0.f, 0.f};
        float lp[4] = {0.f, 0.f, 0.f, 0.f};

        __syncthreads();
        {
            #pragma unroll
            for (int ci = 0; ci < 4; ci++) {
                int chunk = wave * 4 + ci;
                int krow = chunk * 4 + (lane >> 4);
                int kcb = (lane & 15) ^ (krow & 7);
                g2lds16(khead + (size_t)krow * D_ + kcb * 8, &Ks[0][chunk * 512] + lane * 8);
                int vrow = chunk * 8 + (lane >> 3);
                int vcb = (lane & 7) ^ (vrow & 7);
                g2lds16(vhead + (size_t)vrow * L_ + vcb * 8, &Vs[0][chunk * 512] + lane * 8);
            }
        }

        int nk = t + 1;
        for (int j = 0; j < nk; j++) {
            int buf = j & 1;
            __syncthreads();
            if (j + 1 < nk) {
                int k0 = (j + 1) * 64;
                #pragma unroll
                for (int ci = 0; ci < 4; ci++) {
                    int chunk = wave * 4 + ci;
                    int krow = chunk * 4 + (lane >> 4);
                    int kcb = (lane & 15) ^ (krow & 7);
                    g2lds16(khead + (size_t)(k0 + krow) * D_ + kcb * 8,
                            &Ks[buf ^ 1][chunk * 512] + lane * 8);
                    int vrow = chunk * 8 + (lane >> 3);
                    int vcb = (lane & 7) ^ (vrow & 7);
                    g2lds16(vhead + (size_t)vrow * L_ + k0 + vcb * 8,
                            &Vs[buf ^ 1][chunk * 512] + lane * 8);
                }
            }

            f32x4 s[4];
            #pragma unroll
            for (int nt = 0; nt < 4; nt++) {
                s[nt] = (f32x4){0.f, 0.f, 0.f, 0.f};
                int row = nt * 16 + l16;
                #pragma unroll
                for (int kk = 0; kk < 4; kk++) {
                    int cb = (kk * 4 + quad) ^ (row & 7);
                    s[nt] = __builtin_amdgcn_mfma_f32_16x16x32_bf16(
                        aq[kk], ld16(&Ks[buf][row * 128 + cb * 8]), s[nt], 0, 0, 0);
                }
            }
            bool last = (j == nk - 1);
            #pragma unroll
            for (int nt = 0; nt < 4; nt++) {
                int key = j * 64 + nt * 16 + l16;
                #pragma unroll
                for (int r = 0; r < 4; r++) {
                    float v = s[nt][r] - C_MAX;
                    if (last && key > (qrow0 + quad * 4 + r)) v = NEG_INF_;
                    float pe = __builtin_amdgcn_exp2f(v);
                    lp[r] += pe;
                    ldsP[wave][quad * 4 + r][nt * 16 + l16] = f2bf_fast(pe);
                }
            }
            #pragma unroll
            for (int kk2 = 0; kk2 < 2; kk2++) {
                bf16x8 pa = ld16(&ldsP[wave][l16][kk2 * 32 + quad * 8]);
                #pragma unroll
                for (int ont = 0; ont < 8; ont++) {
                    int vrow = ont * 16 + l16;
                    int cb = (kk2 * 4 + quad) ^ (vrow & 7);
                    o[ont] = __builtin_amdgcn_mfma_f32_16x16x32_bf16(
                        pa, ld16(&Vs[buf][vrow * 64 + cb * 8]), o[ont], 0, 0, 0);
                }
            }
        }
        #pragma unroll
        for (int r = 0; r < 4; r++) {
            float v = lp[r];
            v += __shfl_xor(v, 1);
            v += __shfl_xor(v, 2);
            v += __shfl_xor(v, 4);
            v += __shfl_xor(v, 8);
            float inv = 1.0f / v;
            int row = b * L_ + qrow0 + quad * 4 + r;
            #pragma unroll
            for (int ont = 0; ont < 8; ont++)
                Out[row * (HQ_ * D_) + h * D_ + ont * 16 + l16] = f2bf(o[ont][r] * inv);
        }
    }
}

extern "C" void kernel_launch(void* const* d_in, const int* in_sizes, int n_in,
                              void* d_out, int out_size, void* d_ws, size_t ws_size,
                              hipStream_t stream) {
    const float* hs = (const float*)d_in[0];
    const float* Wq = (const float*)d_in[1];
    const float* bq = (const float*)d_in[2];
    const float* Wk = (const float*)d_in[3];
    const float* bk = (const float*)d_in[4];
    const float* Wv = (const float*)d_in[5];
    const float* bv = (const float*)d_in[6];
    const float* Wo = (const float*)d_in[7];
    float* out = (float*)d_out;

    char* ws = (char*)d_ws;
    ushort_t* Wqkv_t = (ushort_t*)(ws);                          // 10485760
    ushort_t* Wo_t   = (ushort_t*)(ws + 10485760);               // 8388608  (end 18874368)
    float*    biasf  = (float*)(ws + 18874368);                  // (end 18884608)
    ushort_t* hsb    = (ushort_t*)(ws + 18884608);               // 16777216 (end 35661824)
    ushort_t* qkv    = (ushort_t*)(ws + 35661824);               // 20971520 (end 56633344)
    ushort_t* Qb     = (ushort_t*)(ws + 56633344);               // 16777216 (end 73410560)
    ushort_t* Kb     = (ushort_t*)(ws + 73410560);               // 2097152  (end 75507712)
    ushort_t* Vt     = (ushort_t*)(ws + 75507712);               // 2097152  (end 77604864)
    ushort_t* attn   = (ushort_t*)(ws + 77604864);               // 16777216 (end 94382080)

    // fused preprocessing: cast + weight transposes + bias
    prep<<<dim3(17418), 256, 0, stream>>>(hs, Wq, Wk, Wv, Wo, bq, bk, bv,
                                          hsb, Wqkv_t, Wo_t, biasf);

    // QKV projection: [4096][2560] bf16 (LDS-staged, 64x128 tile -> 1280 blocks = 5/CU)
    gemm_lds<false><<<dim3(NQKV / 128, (B_ * L_) / 64), 256, 0, stream>>>(hsb, Wqkv_t, biasf, qkv,
                                                                          B_ * L_, NQKV, E_);
    // fused rope_q + rope_k + V transposes
    mid<<<dim3(19456), 256, 0, stream>>>(qkv, Qb, Kb, Vt);

    // flash attention (LDS-staged, double-buffered, balanced pairs + XCD swizzle)
    flash_attn<<<dim3(512), 256, 0, stream>>>(Qb, Kb, Vt, attn);

    // output projection -> d_out (fp32, LDS-staged, 1024 blocks = 4/CU)
    gemm_lds<true><<<dim3(E_ / 128, (B_ * L_) / 64), 256, 0, stream>>>(attn, Wo_t, nullptr, out,
                                                                       B_ * L_, E_, HQ_ * D_);
}

// Round 8
// 300.272 us; speedup vs baseline: 1.0476x; 1.0476x over previous
//
#include <hip/hip_runtime.h>
#include <hip/hip_bf16.h>

typedef unsigned short ushort_t;
typedef unsigned int u32;
typedef __bf16 bf16x8 __attribute__((ext_vector_type(8)));
typedef float f32x4 __attribute__((ext_vector_type(4)));

#define B_ 2
#define L_ 2048
#define E_ 2048
#define HQ_ 16
#define HKV_ 2
#define D_ 128
#define NQKV 2560   // HQ*D + 2*HKV*D
#define SCALE 0.08838834764831845f
#define LOG2E 1.4426950408889634f
#define C_MAX 14.426950408889634f   // 10 * log2(e): fixed softmax max (scores |S| <~ 5)
#define NEG_INF_ -1e30f

__device__ __forceinline__ ushort_t f2bf(float f) {
    unsigned int u = __builtin_bit_cast(unsigned int, f);
    u = (u + 0x7fffu + ((u >> 16) & 1u)) >> 16;
    return (ushort_t)u;
}
__device__ __forceinline__ ushort_t f2bf_fast(float f) {
    unsigned int u = __builtin_bit_cast(unsigned int, f);
    return (ushort_t)((u + 0x8000u) >> 16);
}
__device__ __forceinline__ float bf2f(ushort_t u) {
    return __builtin_bit_cast(float, (unsigned int)u << 16);
}
__device__ __forceinline__ bf16x8 ld16(const ushort_t* p) {
    uint4 u = *reinterpret_cast<const uint4*>(p);
    return __builtin_bit_cast(bf16x8, u);
}
// async global->LDS, 16B per lane; lds dest lands at wave-uniform base + lane*16
__device__ __forceinline__ void g2lds16(const ushort_t* g, ushort_t* l) {
    __builtin_amdgcn_global_load_lds((const __attribute__((address_space(1))) u32*)g,
                                     (__attribute__((address_space(3))) u32*)l, 16, 0, 0);
}

// ================= prep: hs cast + 4 weight transposes + bias concat (fused) ==========
__global__ __launch_bounds__(256) void prep(const float* __restrict__ hs,
                                            const float* __restrict__ Wq,
                                            const float* __restrict__ Wk,
                                            const float* __restrict__ Wv,
                                            const float* __restrict__ Wo,
                                            const float* __restrict__ bq,
                                            const float* __restrict__ bk,
                                            const float* __restrict__ bv,
                                            ushort_t* __restrict__ hsb,
                                            ushort_t* __restrict__ Wqkv_t,
                                            ushort_t* __restrict__ Wo_t,
                                            float* __restrict__ biasf) {
    __shared__ float tile[32][33];
    int bid = blockIdx.x;
    if (bid < 8192) {   // cast hs -> bf16, float4/thread
        int i = bid * 256 + threadIdx.x;
        float4 f = reinterpret_cast<const float4*>(hs)[i];
        ushort4 u;
        u.x = f2bf(f.x); u.y = f2bf(f.y); u.z = f2bf(f.z); u.w = f2bf(f.w);
        reinterpret_cast<ushort4*>(hsb)[i] = u;
        return;
    }
    if (bid >= 17408) {  // bias concat
        int n = (bid - 17408) * 256 + threadIdx.x;
        if (n < NQKV) {
            float v;
            if (n < 2048) v = bq[n];
            else if (n < 2304) v = bk[n - 2048];
            else v = bv[n - 2304];
            biasf[n] = v;
        }
        return;
    }
    const float* in; ushort_t* out; int in_stride, gx, gy;
    if (bid < 12288)      { int t = bid - 8192;  gx = t & 63; gy = t >> 6; in = Wq; out = Wqkv_t;               in_stride = 2048; }
    else if (bid < 12800) { int t = bid - 12288; gx = t & 7;  gy = t >> 3; in = Wk; out = Wqkv_t + 2048 * 2048; in_stride = 256;  }
    else if (bid < 13312) { int t = bid - 12800; gx = t & 7;  gy = t >> 3; in = Wv; out = Wqkv_t + 2304 * 2048; in_stride = 256;  }
    else                  { int t = bid - 13312; gx = t & 63; gy = t >> 6; in = Wo; out = Wo_t;                 in_stride = 2048; }
    int tx = threadIdx.x & 31, ty = threadIdx.x >> 5;
    int c0 = gx * 32, r0 = gy * 32;
    #pragma unroll
    for (int k = 0; k < 4; k++)
        tile[ty + k * 8][tx] = in[(size_t)(r0 + ty + k * 8) * in_stride + c0 + tx];
    __syncthreads();
    #pragma unroll
    for (int k = 0; k < 4; k++)
        out[(size_t)(c0 + ty + k * 8) * 2048 + r0 + tx] = f2bf(tile[tx][ty + k * 8]);
}

// ================= mid: rope_q + rope_k + V transposes (fused) =========================
__global__ __launch_bounds__(256) void mid(const ushort_t* __restrict__ qkv,
                                           ushort_t* __restrict__ Q,
                                           ushort_t* __restrict__ K,
                                           ushort_t* __restrict__ Vt) {
    __shared__ ushort_t tile[32][33];
    int bid = blockIdx.x;
    if (bid < 16384) {   // rope_q (pre-scaled by SCALE*log2e for exp2-domain softmax)
        int idx = bid * 256 + threadIdx.x;
        int i = idx & 63;
        int h = (idx >> 6) & 15;
        int l = (idx >> 10) & 2047;
        int b = idx >> 21;
        const ushort_t* src = qkv + (size_t)(b * L_ + l) * NQKV + h * D_;
        float x1 = bf2f(src[i]), x2 = bf2f(src[i + 64]);
        float invf = __expf(-(float)i * (13.815510557964274f / 64.0f));
        float fr = (float)l * invf;
        float c = cosf(fr), s = sinf(fr);
        ushort_t* dst = Q + (size_t)((b * HQ_ + h) * L_ + l) * D_;
        const float SC = SCALE * LOG2E;
        dst[i] = f2bf((x1 * c - x2 * s) * SC);
        dst[i + 64] = f2bf((x2 * c + x1 * s) * SC);
        return;
    }
    if (bid < 18432) {   // rope_k
        int idx = (bid - 16384) * 256 + threadIdx.x;
        int i = idx & 63;
        int h = (idx >> 6) & 1;
        int l = (idx >> 7) & 2047;
        int b = idx >> 18;
        const ushort_t* src = qkv + (size_t)(b * L_ + l) * NQKV + 2048 + h * D_;
        float x1 = bf2f(src[i]), x2 = bf2f(src[i + 64]);
        float invf = __expf(-(float)i * (13.815510557964274f / 64.0f));
        float fr = (float)l * invf;
        float c = cosf(fr), s = sinf(fr);
        ushort_t* dst = K + (size_t)((b * HKV_ + h) * L_ + l) * D_;
        dst[i] = f2bf(x1 * c - x2 * s);
        dst[i + 64] = f2bf(x2 * c + x1 * s);
        return;
    }
    // V transpose: Vt[b][kv][d][l] = qkv[b,l][2304 + kv*128 + d]
    int t = bid - 18432;           // [0,1024)
    int z = t >> 8, rem = t & 255;
    int gx = rem & 3, gy = rem >> 2;
    int b = z >> 1, kvh = z & 1;
    const ushort_t* in = qkv + (size_t)(b * L_) * NQKV + 2304 + kvh * D_;
    ushort_t* out = Vt + (size_t)(b * HKV_ + kvh) * D_ * L_;
    int tx = threadIdx.x & 31, ty = threadIdx.x >> 5;
    int c0 = gx * 32, r0 = gy * 32;
    #pragma unroll
    for (int k = 0; k < 4; k++)
        tile[ty + k * 8][tx] = in[(size_t)(r0 + ty + k * 8) * NQKV + c0 + tx];
    __syncthreads();
    #pragma unroll
    for (int k = 0; k < 4; k++)
        out[(size_t)(c0 + ty + k * 8) * L_ + r0 + tx] = tile[tx][ty + k * 8];
}

// ---------------- LDS-staged GEMM, tile 128x128, BK=64 (2 K-steps per barrier) --------
// block 256 = 4 waves (2x2), wave tile 64x64. Per K-iter/wave: 8 g2lds16, 16 ds_read_b128,
// 32 MFMA. LDS 32 KB (still >= grid-capped 2.5 blocks/CU resident).
template <bool F32OUT>
__global__ __launch_bounds__(256, 2) void gemm_lds(const ushort_t* __restrict__ A,
                                                   const ushort_t* __restrict__ Bt,
                                                   const float* __restrict__ bias,
                                                   void* __restrict__ Cv,
                                                   int M, int N, int Kd) {
    __shared__ ushort_t As[128 * 64];   // 16 KB, row stride 64 halves (128 B)
    __shared__ ushort_t Bs[128 * 64];   // 16 KB
    int lane = threadIdx.x & 63, wave = threadIdx.x >> 6;
    int quad = lane >> 4, l16 = lane & 15;
    int wm = wave >> 1, wn = wave & 1;
    int m0 = blockIdx.y * 128, n0 = blockIdx.x * 128;

    f32x4 acc[4][4];
    #pragma unroll
    for (int i = 0; i < 4; i++)
        #pragma unroll
        for (int j = 0; j < 4; j++) acc[i][j] = (f32x4){0.f, 0.f, 0.f, 0.f};

    // staging: 16 chunks per matrix; chunk = 8 rows x 128 B; wave w covers chunks [4w,4w+4)
    int rA = lane >> 3;            // row within chunk
    int colh = (lane & 7) * 8;     // halfword col offset
    for (int k0 = 0; k0 < Kd; k0 += 64) {
        __syncthreads();
        #pragma unroll
        for (int q = 0; q < 4; q++) {
            int chunk = wave * 4 + q;
            int row = chunk * 8 + rA;
            g2lds16(A  + (size_t)(m0 + row) * Kd + k0 + colh, As + chunk * 512 + lane * 8);
            g2lds16(Bt + (size_t)(n0 + row) * Kd + k0 + colh, Bs + chunk * 512 + lane * 8);
        }
        __syncthreads();
        #pragma unroll
        for (int kk = 0; kk < 2; kk++) {
            bf16x8 af[4], bfr[4];
            #pragma unroll
            for (int i = 0; i < 4; i++)
                af[i]  = ld16(As + (wm * 64 + i * 16 + l16) * 64 + kk * 32 + quad * 8);
            #pragma unroll
            for (int j = 0; j < 4; j++)
                bfr[j] = ld16(Bs + (wn * 64 + j * 16 + l16) * 64 + kk * 32 + quad * 8);
            #pragma unroll
            for (int i = 0; i < 4; i++)
                #pragma unroll
                for (int j = 0; j < 4; j++)
                    acc[i][j] = __builtin_amdgcn_mfma_f32_16x16x32_bf16(af[i], bfr[j], acc[i][j], 0, 0, 0);
        }
    }

    #pragma unroll
    for (int i = 0; i < 4; i++) {
        #pragma unroll
        for (int j = 0; j < 4; j++) {
            #pragma unroll
            for (int r = 0; r < 4; r++) {
                int row = m0 + wm * 64 + 16 * i + quad * 4 + r;
                int col = n0 + wn * 64 + 16 * j + l16;
                float v = acc[i][j][r];
                if (bias) v += bias[col];
                if (F32OUT) ((float*)Cv)[(size_t)row * N + col] = v;
                else        ((ushort_t*)Cv)[(size_t)row * N + col] = f2bf(v);
            }
        }
    }
}

// ---------------- flash attention: LDS-staged K/V, double-buffered, fixed-max softmax ----
__global__ __launch_bounds__(256, 2) void flash_attn(const ushort_t* __restrict__ Q,
                                                     const ushort_t* __restrict__ K,
                                                     const ushort_t* __restrict__ Vt,
                                                     ushort_t* __restrict__ Out) {
    __shared__ ushort_t Ks[2][64 * 128];
    __shared__ ushort_t Vs[2][128 * 64];
    __shared__ ushort_t ldsP[4][16][72];

    int idx = blockIdx.x;
    int x = idx & 7, j5 = idx >> 3;
    int cc = x >> 1, sub = x & 1;
    int hh = (j5 & 3) * 2 + sub;
    int p = j5 >> 2;
    int b = cc >> 1, kv = cc & 1;
    int h = kv * 8 + hh;

    int lane = threadIdx.x & 63, wave = threadIdx.x >> 6;
    int quad = lane >> 4, l16 = lane & 15;

    const ushort_t* khead = K + (b * HKV_ + kv) * L_ * D_;
    const ushort_t* vhead = Vt + (b * HKV_ + kv) * D_ * L_;

    #pragma unroll 1
    for (int ti = 0; ti < 2; ti++) {
        int t = ti ? (31 - p) : p;
        int qrow0 = t * 64 + wave * 16;

        bf16x8 aq[4];
        const ushort_t* qbase = Q + ((b * HQ_ + h) * L_ + qrow0 + l16) * D_ + quad * 8;
        #pragma unroll
        for (int kk = 0; kk < 4; kk++) aq[kk] = ld16(qbase + 32 * kk);

        f32x4 o[8];
        #pragma unroll
        for (int i = 0; i < 8; i++) o[i] = (f32x4){0.f, 0.f, 0.f, 0.f};
        float lp[4] = {0.f, 0.f, 0.f, 0.f};

        __syncthreads();
        {
            #pragma unroll
            for (int ci = 0; ci < 4; ci++) {
                int chunk = wave * 4 + ci;
                int krow = chunk * 4 + (lane >> 4);
                int kcb = (lane & 15) ^ (krow & 7);
                g2lds16(khead + (size_t)krow * D_ + kcb * 8, &Ks[0][chunk * 512] + lane * 8);
                int vrow = chunk * 8 + (lane >> 3);
                int vcb = (lane & 7) ^ (vrow & 7);
                g2lds16(vhead + (size_t)vrow * L_ + vcb * 8, &Vs[0][chunk * 512] + lane * 8);
            }
        }

        int nk = t + 1;
        for (int j = 0; j < nk; j++) {
            int buf = j & 1;
            __syncthreads();
            if (j + 1 < nk) {
                int k0 = (j + 1) * 64;
                #pragma unroll
                for (int ci = 0; ci < 4; ci++) {
                    int chunk = wave * 4 + ci;
                    int krow = chunk * 4 + (lane >> 4);
                    int kcb = (lane & 15) ^ (krow & 7);
                    g2lds16(khead + (size_t)(k0 + krow) * D_ + kcb * 8,
                            &Ks[buf ^ 1][chunk * 512] + lane * 8);
                    int vrow = chunk * 8 + (lane >> 3);
                    int vcb = (lane & 7) ^ (vrow & 7);
                    g2lds16(vhead + (size_t)vrow * L_ + k0 + vcb * 8,
                            &Vs[buf ^ 1][chunk * 512] + lane * 8);
                }
            }

            f32x4 s[4];
            #pragma unroll
            for (int nt = 0; nt < 4; nt++) {
                s[nt] = (f32x4){0.f, 0.f, 0.f, 0.f};
                int row = nt * 16 + l16;
                #pragma unroll
                for (int kk = 0; kk < 4; kk++) {
                    int cb = (kk * 4 + quad) ^ (row & 7);
                    s[nt] = __builtin_amdgcn_mfma_f32_16x16x32_bf16(
                        aq[kk], ld16(&Ks[buf][row * 128 + cb * 8]), s[nt], 0, 0, 0);
                }
            }
            bool last = (j == nk - 1);
            #pragma unroll
            for (int nt = 0; nt < 4; nt++) {
                int key = j * 64 + nt * 16 + l16;
                #pragma unroll
                for (int r = 0; r < 4; r++) {
                    float v = s[nt][r] - C_MAX;
                    if (last && key > (qrow0 + quad * 4 + r)) v = NEG_INF_;
                    float pe = __builtin_amdgcn_exp2f(v);
                    lp[r] += pe;
                    ldsP[wave][quad * 4 + r][nt * 16 + l16] = f2bf_fast(pe);
                }
            }
            #pragma unroll
            for (int kk2 = 0; kk2 < 2; kk2++) {
                bf16x8 pa = ld16(&ldsP[wave][l16][kk2 * 32 + quad * 8]);
                #pragma unroll
                for (int ont = 0; ont < 8; ont++) {
                    int vrow = ont * 16 + l16;
                    int cb = (kk2 * 4 + quad) ^ (vrow & 7);
                    o[ont] = __builtin_amdgcn_mfma_f32_16x16x32_bf16(
                        pa, ld16(&Vs[buf][vrow * 64 + cb * 8]), o[ont], 0, 0, 0);
                }
            }
        }
        #pragma unroll
        for (int r = 0; r < 4; r++) {
            float v = lp[r];
            v += __shfl_xor(v, 1);
            v += __shfl_xor(v, 2);
            v += __shfl_xor(v, 4);
            v += __shfl_xor(v, 8);
            float inv = 1.0f / v;
            int row = b * L_ + qrow0 + quad * 4 + r;
            #pragma unroll
            for (int ont = 0; ont < 8; ont++)
                Out[row * (HQ_ * D_) + h * D_ + ont * 16 + l16] = f2bf(o[ont][r] * inv);
        }
    }
}

extern "C" void kernel_launch(void* const* d_in, const int* in_sizes, int n_in,
                              void* d_out, int out_size, void* d_ws, size_t ws_size,
                              hipStream_t stream) {
    const float* hs = (const float*)d_in[0];
    const float* Wq = (const float*)d_in[1];
    const float* bq = (const float*)d_in[2];
    const float* Wk = (const float*)d_in[3];
    const float* bk = (const float*)d_in[4];
    const float* Wv = (const float*)d_in[5];
    const float* bv = (const float*)d_in[6];
    const float* Wo = (const float*)d_in[7];
    float* out = (float*)d_out;

    char* ws = (char*)d_ws;
    ushort_t* Wqkv_t = (ushort_t*)(ws);                          // 10485760
    ushort_t* Wo_t   = (ushort_t*)(ws + 10485760);               // 8388608  (end 18874368)
    float*    biasf  = (float*)(ws + 18874368);                  // (end 18884608)
    ushort_t* hsb    = (ushort_t*)(ws + 18884608);               // 16777216 (end 35661824)
    ushort_t* qkv    = (ushort_t*)(ws + 35661824);               // 20971520 (end 56633344)
    ushort_t* Qb     = (ushort_t*)(ws + 56633344);               // 16777216 (end 73410560)
    ushort_t* Kb     = (ushort_t*)(ws + 73410560);               // 2097152  (end 75507712)
    ushort_t* Vt     = (ushort_t*)(ws + 75507712);               // 2097152  (end 77604864)
    ushort_t* attn   = (ushort_t*)(ws + 77604864);               // 16777216 (end 94382080)

    // fused preprocessing: cast + weight transposes + bias
    prep<<<dim3(17418), 256, 0, stream>>>(hs, Wq, Wk, Wv, Wo, bq, bk, bv,
                                          hsb, Wqkv_t, Wo_t, biasf);

    // QKV projection: [4096][2560] bf16 (LDS-staged, 128x128 tile, BK=64)
    gemm_lds<false><<<dim3(NQKV / 128, (B_ * L_) / 128), 256, 0, stream>>>(hsb, Wqkv_t, biasf, qkv,
                                                                           B_ * L_, NQKV, E_);
    // fused rope_q + rope_k + V transposes
    mid<<<dim3(19456), 256, 0, stream>>>(qkv, Qb, Kb, Vt);

    // flash attention (LDS-staged, double-buffered, balanced pairs + XCD swizzle)
    flash_attn<<<dim3(512), 256, 0, stream>>>(Qb, Kb, Vt, attn);

    // output projection -> d_out (fp32, LDS-staged, 128x128 tile, BK=64)
    gemm_lds<true><<<dim3(E_ / 128, (B_ * L_) / 128), 256, 0, stream>>>(attn, Wo_t, nullptr, out,
                                                                        B_ * L_, E_, HQ_ * D_);
}